// Round 19
// baseline (549.445 us; speedup 1.0000x reference)
//
#include <hip/hip_runtime.h>
#include <hip/hip_bf16.h>

// Problem constants fixed by setup_inputs()
#define NNODE   20000
#define BS      8
#define NEG1    33
#define DDIM    32
#define NLAYER  6
#define NRELX2  128     // 2*N_REL
#define FEAT    256     // BS*DDIM
#define INW     416     // 13*DDIM
#define NPB     8       // nodes per block -> 64 A-rows (2 tiles/wave), grid 2500
#define BPSZ    (13 * 2 * 2 * 64 * 8)   // per-layer packed-B ushorts (26624)
#define SCB     ((NNODE + 255) / 256)   // scan blocks (79)

typedef __attribute__((ext_vector_type(8))) short s16x8;
typedef __attribute__((ext_vector_type(4))) float f32x4;

__device__ inline unsigned short bf16_rn(float f) {
    unsigned u = __float_as_uint(f);
    u += 0x7FFF + ((u >> 16) & 1);
    return (unsigned short)(u >> 16);
}
__device__ inline float bf16_f(unsigned short h) {
    return __uint_as_float(((unsigned)h) << 16);
}

// ---------------------------------------------------------------- precompute
__global__ void count_kernel(const int* __restrict__ es, const int* __restrict__ ed,
                             int* __restrict__ cnt, int E) {
    int i = blockIdx.x * 256 + threadIdx.x;
    if (i >= 2 * E) return;
    int dst = (i < E) ? ed[i] : es[i - E];
    atomicAdd(&cnt[dst], 1);
}

// hierarchical scan: A) per-block inclusive scan + block sums
__global__ void scanA_kernel(const int* __restrict__ cnt, int* __restrict__ row_ptr,
                             int* __restrict__ bsum, int N) {
    __shared__ int sh[256];
    int i = blockIdx.x * 256 + threadIdx.x;
    int v = (i < N) ? cnt[i] : 0;
    sh[threadIdx.x] = v;
    __syncthreads();
    #pragma unroll
    for (int off = 1; off < 256; off <<= 1) {
        int t = (threadIdx.x >= off) ? sh[threadIdx.x - off] : 0;
        __syncthreads();
        sh[threadIdx.x] += t;
        __syncthreads();
    }
    if (i < N) row_ptr[i + 1] = sh[threadIdx.x];
    if (threadIdx.x == 255) bsum[blockIdx.x] = sh[255];
}

// B) exclusive scan of block sums (one small block)
__global__ void scanB_kernel(int* __restrict__ bsum, int NB) {
    __shared__ int sh[128];
    int t = threadIdx.x;
    int v = (t < NB) ? bsum[t] : 0;
    sh[t] = v;
    __syncthreads();
    #pragma unroll
    for (int off = 1; off < 128; off <<= 1) {
        int x = (t >= off) ? sh[t - off] : 0;
        __syncthreads();
        sh[t] += x;
        __syncthreads();
    }
    if (t < NB) bsum[t] = sh[t] - v;   // exclusive
}

// C) add block offsets
__global__ void scanC_kernel(const int* __restrict__ bsum, int* __restrict__ row_ptr, int N) {
    int i = blockIdx.x * 256 + threadIdx.x;
    if (i == 0) row_ptr[0] = 0;
    if (i < N) row_ptr[i + 1] += bsum[blockIdx.x];
}

// csr_pack = (src << 16) | etype   (src < 20000 < 65536, etype < 128)
__global__ void fill_kernel(const int* __restrict__ es, const int* __restrict__ ed,
                            const int* __restrict__ et, const int* __restrict__ row_ptr,
                            int* __restrict__ cursor, int* __restrict__ csr_pack, int E) {
    int i = blockIdx.x * 256 + threadIdx.x;
    if (i >= 2 * E) return;
    int src, dst, ty;
    if (i < E) { src = es[i]; dst = ed[i]; ty = et[i]; }
    else       { src = ed[i - E]; dst = es[i - E]; ty = et[i - E] + 64; }
    int pos = row_ptr[dst] + atomicAdd(&cursor[dst], 1);
    csr_pack[pos] = (src << 16) | ty;
}

__global__ void deg_kernel(const int* __restrict__ cnt, float* __restrict__ dinv,
                           float* __restrict__ logdeg, int N) {
    int n = blockIdx.x * 256 + threadIdx.x;
    if (n >= N) return;
    float deg = (float)cnt[n] + 1.0f;
    dinv[n] = 1.0f / deg;
    logdeg[n] = logf(deg);
}

__global__ void mean_kernel(const float* __restrict__ logdeg, float* __restrict__ meanout, int N) {
    __shared__ float sh[256];
    float s = 0.f;
    for (int i = threadIdx.x; i < N; i += 256) s += logdeg[i];
    sh[threadIdx.x] = s;
    __syncthreads();
    for (int off = 128; off > 0; off >>= 1) {
        if (threadIdx.x < off) sh[threadIdx.x] += sh[threadIdx.x + off];
        __syncthreads();
    }
    if (threadIdx.x == 0) meanout[0] = sh[0] / (float)N;
}

__global__ void sc_kernel(const float* __restrict__ logdeg, const float* __restrict__ meanp,
                          float* __restrict__ sc, int N) {
    int n = blockIdx.x * 256 + threadIdx.x;
    if (n >= N) return;
    sc[n] = logdeg[n] / meanp[0];
}

__global__ void prep_kernel(const int* __restrict__ h_index, const int* __restrict__ t_index,
                            const int* __restrict__ r_index, const float* __restrict__ rel_query,
                            int* __restrict__ h0, int* __restrict__ r0,
                            float* __restrict__ query, int* __restrict__ tnew) {
    __shared__ int s_isneg[BS];
    __shared__ int s_r0[BS];
    int t = threadIdx.x;
    if (t < BS) {
        int b = t;
        int hv = h_index[b * NEG1];
        int all = 1;
        for (int j = 1; j < NEG1; j++) all &= (h_index[b * NEG1 + j] == hv);
        s_isneg[b] = all;
        int h0v = all ? hv : t_index[b * NEG1];
        int r0v = all ? r_index[b * NEG1] : r_index[b * NEG1] + 64;
        s_r0[b] = r0v;
        h0[b] = h0v;
        r0[b] = r0v;
    }
    __syncthreads();
    {
        int b = t >> 5, dd = t & 31;
        query[t] = rel_query[s_r0[b] * DDIM + dd];
    }
    for (int idx = t; idx < BS * NEG1; idx += 256) {
        int b = idx / NEG1;
        tnew[idx] = s_isneg[b] ? t_index[idx] : h_index[idx];
    }
}

__global__ void rel_kernel(const float* __restrict__ rel_query, const float* __restrict__ Wrel,
                           const float* __restrict__ brel, float* __restrict__ rel_all) {
    int idx = blockIdx.x * 256 + threadIdx.x;
    if (idx >= NLAYER * NRELX2 * DDIM) return;
    int i  = idx >> 12;          // / 4096
    int q  = (idx >> 5) & 127;
    int dd = idx & 31;
    float acc = brel[i * DDIM + dd];
    #pragma unroll
    for (int k = 0; k < DDIM; k++)
        acc = fmaf(rel_query[q * DDIM + k], Wrel[i * DDIM * DDIM + k * DDIM + dd], acc);
    rel_all[idx] = acc;
}

// Packed split-bf16 B fragments for mfma_f32_16x16x32_bf16.
// Flat layout: ((((layer*13 + j)*2 + half)*2 + term)*64 + lane)*8 + e
__global__ void bpack_kernel(const float* __restrict__ Wlin, unsigned short* __restrict__ bp) {
    int idx = blockIdx.x * 256 + threadIdx.x;
    if (idx >= NLAYER * BPSZ) return;
    int e    = idx & 7;
    int lane = (idx >> 3) & 63;
    int term = (idx >> 9) & 1;
    int half = (idx >> 10) & 1;
    int jl   = idx >> 11;
    int j    = jl % 13;
    int layer = jl / 13;
    int col = half * 16 + (lane & 15);
    int kk  = (lane >> 4) * 8 + e;
    int row;
    if (j == 0) row = kk;
    else { int s = (j - 1) & 3, scl = (j - 1) >> 2; row = 32 + (kk * 4 + s) * 3 + scl; }
    float wv = Wlin[(layer * INW + row) * DDIM + col];
    unsigned short hi = bf16_rn(wv);
    bp[idx] = (term == 0) ? hi : bf16_rn(wv - bf16_f(hi));
}

__global__ void init_x_kernel(float* __restrict__ x, const int* __restrict__ h0,
                              const float* __restrict__ query) {
    int i = blockIdx.x * 256 + threadIdx.x;
    if (i >= NNODE * FEAT) return;
    int n = i >> 8;
    int t = i & 255;
    int b = t >> 5;
    x[i] = (h0[b] == n) ? query[t] : 0.f;
}

// ---------------------------------------------------------------- main layer
// 8 nodes/block -> 64 A-rows. Each wave: one col-half, TWO 16-row tiles with
// shared B registers (B L2 traffic halved, 78 MFMA/wave). C planes overlay
// the A buffer after the MFMA reads.

#define STATS_COMP(U, NODE) {                                                 \
    int n_ = (NODE);                                                          \
    float bv_ = (h0b == n_) ? q : 0.f;                                        \
    float sum_ = bv_, ssq_ = bv_ * bv_, vmx_ = bv_, vmn_ = bv_;               \
    int e0_ = row_ptr[n_], e1_ = row_ptr[n_ + 1];                             \
    xm##U = x_in[n_ * FEAT + t];                                              \
    int e_ = e0_;                                                             \
    for (; e_ + 3 < e1_; e_ += 4) {                                           \
        int pa_ = csr_pack[e_];                                               \
        int pb_ = csr_pack[e_ + 1];                                           \
        int pc_ = csr_pack[e_ + 2];                                           \
        int pd_ = csr_pack[e_ + 3];                                           \
        float xa_ = x_in[(pa_ >> 16) * FEAT + t];                             \
        float xb_ = x_in[(pb_ >> 16) * FEAT + t];                             \
        float xc_ = x_in[(pc_ >> 16) * FEAT + t];                             \
        float xd_ = x_in[(pd_ >> 16) * FEAT + t];                             \
        float ra_ = rel_i[((pa_ & 0xFFFF) << 5) + dd];                        \
        float rb_ = rel_i[((pb_ & 0xFFFF) << 5) + dd];                        \
        float rc_ = rel_i[((pc_ & 0xFFFF) << 5) + dd];                        \
        float rd_ = rel_i[((pd_ & 0xFFFF) << 5) + dd];                        \
        float ma_ = xa_ * ra_, mb_ = xb_ * rb_;                               \
        float mc_ = xc_ * rc_, md_ = xd_ * rd_;                               \
        sum_ += ((ma_ + mb_) + (mc_ + md_));                                  \
        ssq_ = fmaf(ma_, ma_, ssq_); ssq_ = fmaf(mb_, mb_, ssq_);             \
        ssq_ = fmaf(mc_, mc_, ssq_); ssq_ = fmaf(md_, md_, ssq_);             \
        vmx_ = fmaxf(vmx_, fmaxf(fmaxf(ma_, mb_), fmaxf(mc_, md_)));         \
        vmn_ = fminf(vmn_, fminf(fminf(ma_, mb_), fminf(mc_, md_)));         \
    }                                                                         \
    for (; e_ < e1_; ++e_) {                                                  \
        int p_  = csr_pack[e_];                                               \
        float m_ = x_in[(p_ >> 16) * FEAT + t]                                \
                   * rel_i[((p_ & 0xFFFF) << 5) + dd];                        \
        sum_ += m_; ssq_ = fmaf(m_, m_, ssq_);                                \
        vmx_ = fmaxf(vmx_, m_); vmn_ = fminf(vmn_, m_);                       \
    }                                                                         \
    float dv_ = dinv[n_];                                                     \
    mean##U = sum_ * dv_;                                                     \
    float sq_ = ssq_ * dv_;                                                   \
    mx##U = vmx_; mn##U = vmn_;                                               \
    sd##U = sqrtf(fmaxf(sq_ - mean##U * mean##U, 1e-6f));                     \
    float sv_ = sc[n_];                                                       \
    sv##U = sv_; s2##U = 1.0f / fmaxf(sv_, 0.01f);                            \
}

#define SDECL(U) float xm##U, mean##U, mx##U, mn##U, sd##U, sv##U, s2##U;

#define AW1(ROW, C, V) {                                                      \
    unsigned short h_ = bf16_rn(V);                                           \
    s_A[0][ROW][(C) * 32 + dd] = h_;                                          \
    s_A[1][ROW][(C) * 32 + dd] = bf16_rn((V) - bf16_f(h_));                   \
}

#define AWRITE(U, NL) {                                                       \
    int row_ = (NL) * 8 + b;                                                  \
    AW1(row_, 0, xm##U)                                                       \
    AW1(row_, 1, mean##U)                                                     \
    AW1(row_, 2, mx##U)                                                       \
    AW1(row_, 3, mn##U)                                                       \
    AW1(row_, 4, sd##U)                                                       \
}

#define LNF(U, NL) {                                                          \
    int row_ = (NL) * 8 + b;                                                  \
    float v_ = s_C[row_ * 33 + dd]                                            \
             + sv##U * s_C[2112 + row_ * 33 + dd]                             \
             + s2##U * s_C[4224 + row_ * 33 + dd] + bl;                       \
    float s1_ = v_;                                                           \
    s1_ += __shfl_xor(s1_, 16, 32); s1_ += __shfl_xor(s1_, 8, 32);            \
    s1_ += __shfl_xor(s1_, 4, 32);  s1_ += __shfl_xor(s1_, 2, 32);            \
    s1_ += __shfl_xor(s1_, 1, 32);                                            \
    float lm_ = s1_ * (1.0f / 32.0f);                                         \
    float dl_ = v_ - lm_;                                                     \
    float p2_ = dl_ * dl_;                                                    \
    p2_ += __shfl_xor(p2_, 16, 32); p2_ += __shfl_xor(p2_, 8, 32);            \
    p2_ += __shfl_xor(p2_, 4, 32);  p2_ += __shfl_xor(p2_, 2, 32);            \
    p2_ += __shfl_xor(p2_, 1, 32);                                            \
    float var_ = p2_ * (1.0f / 32.0f);                                        \
    float y_ = dl_ / sqrtf(var_ + 1e-5f) * gdd + bdd;                         \
    y_ = fmaxf(y_, 0.0f);                                                     \
    x_out[(nbase + (NL)) * FEAT + t] = y_ + xm##U;                            \
}

__global__ __launch_bounds__(256, 3) void layer_kernel(
    const float* __restrict__ x_in, float* __restrict__ x_out,
    const int* __restrict__ row_ptr, const int* __restrict__ csr_pack,
    const float* __restrict__ rel_i,           // [128][32], L1-resident
    const unsigned short* __restrict__ bp_i,   // packed split-bf16 B frags
    const float* __restrict__ blin_i, const float* __restrict__ g_i,
    const float* __restrict__ b_i,
    const float* __restrict__ dinv, const float* __restrict__ sc,
    const int* __restrict__ h0, const float* __restrict__ query) {
    int t  = threadIdx.x;
    int b  = t >> 5, dd = t & 31;
    int l  = t & 63;
    int w  = t >> 6;
    // 43 KB: split-bf16 A[2][64][168]; C planes (25.3 KB) overlay after reads.
    __shared__ __align__(16) unsigned short s_A[2][64][168];
    float* s_C = (float*)&s_A[0][0][0];

    float q   = query[t];
    int   h0b = h0[b];
    float gdd = g_i[dd], bdd = b_i[dd], bl = blin_i[dd];

    int nbase = blockIdx.x * NPB;
    SDECL(0) SDECL(1) SDECL(2) SDECL(3)
    SDECL(4) SDECL(5) SDECL(6) SDECL(7)
    STATS_COMP(0, nbase + 0)
    STATS_COMP(1, nbase + 1)
    STATS_COMP(2, nbase + 2)
    STATS_COMP(3, nbase + 3)
    STATS_COMP(4, nbase + 4)
    STATS_COMP(5, nbase + 5)
    STATS_COMP(6, nbase + 6)
    STATS_COMP(7, nbase + 7)

    // phase 2: A rows (split bf16) into LDS
    AWRITE(0, 0) AWRITE(1, 1) AWRITE(2, 2) AWRITE(3, 3)
    AWRITE(4, 4) AWRITE(5, 5) AWRITE(6, 6) AWRITE(7, 7)
    __syncthreads();

    // phase 3: MFMA. wave w: half = w&1, tiles {w>>1, (w>>1)+2}, shared B regs.
    {
        int tile = w >> 1, half = w & 1;
        int arowA = tile * 16 + (l & 15);
        int arowB = arowA + 32;
        int koff = (l >> 4) * 8;
        f32x4 a0A = {0.f,0.f,0.f,0.f}, a1A = {0.f,0.f,0.f,0.f}, a2A = {0.f,0.f,0.f,0.f};
        f32x4 a0B = {0.f,0.f,0.f,0.f}, a1B = {0.f,0.f,0.f,0.f}, a2B = {0.f,0.f,0.f,0.f};
        #pragma unroll
        for (int j = 0; j < 13; ++j) {
            int ac = (j == 0) ? 0 : 1 + ((j - 1) & 3);
            s16x8 ahA = *(const s16x8*)&s_A[0][arowA][ac * 32 + koff];
            s16x8 alA = *(const s16x8*)&s_A[1][arowA][ac * 32 + koff];
            s16x8 ahB = *(const s16x8*)&s_A[0][arowB][ac * 32 + koff];
            s16x8 alB = *(const s16x8*)&s_A[1][arowB][ac * 32 + koff];
            const unsigned short* pb = bp_i + (((j * 2 + half) * 2 + 0) * 64 + l) * 8;
            s16x8 bh = *(const s16x8*)pb;
            s16x8 bl2 = *(const s16x8*)(pb + 512);   // term=1 stride 64*8
            if (j <= 4) {
                a0A = __builtin_amdgcn_mfma_f32_16x16x32_bf16(ahA, bh,  a0A, 0, 0, 0);
                a0A = __builtin_amdgcn_mfma_f32_16x16x32_bf16(ahA, bl2, a0A, 0, 0, 0);
                a0A = __builtin_amdgcn_mfma_f32_16x16x32_bf16(alA, bh,  a0A, 0, 0, 0);
                a0B = __builtin_amdgcn_mfma_f32_16x16x32_bf16(ahB, bh,  a0B, 0, 0, 0);
                a0B = __builtin_amdgcn_mfma_f32_16x16x32_bf16(ahB, bl2, a0B, 0, 0, 0);
                a0B = __builtin_amdgcn_mfma_f32_16x16x32_bf16(alB, bh,  a0B, 0, 0, 0);
            } else if (j <= 8) {
                a1A = __builtin_amdgcn_mfma_f32_16x16x32_bf16(ahA, bh,  a1A, 0, 0, 0);
                a1A = __builtin_amdgcn_mfma_f32_16x16x32_bf16(ahA, bl2, a1A, 0, 0, 0);
                a1A = __builtin_amdgcn_mfma_f32_16x16x32_bf16(alA, bh,  a1A, 0, 0, 0);
                a1B = __builtin_amdgcn_mfma_f32_16x16x32_bf16(ahB, bh,  a1B, 0, 0, 0);
                a1B = __builtin_amdgcn_mfma_f32_16x16x32_bf16(ahB, bl2, a1B, 0, 0, 0);
                a1B = __builtin_amdgcn_mfma_f32_16x16x32_bf16(alB, bh,  a1B, 0, 0, 0);
            } else {
                a2A = __builtin_amdgcn_mfma_f32_16x16x32_bf16(ahA, bh,  a2A, 0, 0, 0);
                a2A = __builtin_amdgcn_mfma_f32_16x16x32_bf16(ahA, bl2, a2A, 0, 0, 0);
                a2A = __builtin_amdgcn_mfma_f32_16x16x32_bf16(alA, bh,  a2A, 0, 0, 0);
                a2B = __builtin_amdgcn_mfma_f32_16x16x32_bf16(ahB, bh,  a2B, 0, 0, 0);
                a2B = __builtin_amdgcn_mfma_f32_16x16x32_bf16(ahB, bl2, a2B, 0, 0, 0);
                a2B = __builtin_amdgcn_mfma_f32_16x16x32_bf16(alB, bh,  a2B, 0, 0, 0);
            }
        }
        __syncthreads();   // all waves done reading A -> safe to overlay C
        // C/D layout (verified): col = lane&15, row = (lane>>4)*4 + reg
        int crowA = tile * 16 + ((l >> 4) << 2);
        int crowB = crowA + 32;
        int ccol = half * 16 + (l & 15);
        #pragma unroll
        for (int r = 0; r < 4; ++r) {
            s_C[(crowA + r) * 33 + ccol]        = a0A[r];
            s_C[2112 + (crowA + r) * 33 + ccol] = a1A[r];
            s_C[4224 + (crowA + r) * 33 + ccol] = a2A[r];
            s_C[(crowB + r) * 33 + ccol]        = a0B[r];
            s_C[2112 + (crowB + r) * 33 + ccol] = a1B[r];
            s_C[4224 + (crowB + r) * 33 + ccol] = a2B[r];
        }
    }
    __syncthreads();

    // phase 4: combine + LayerNorm + ReLU + residual
    LNF(0, 0) LNF(1, 1) LNF(2, 2) LNF(3, 3)
    LNF(4, 4) LNF(5, 5) LNF(6, 6) LNF(7, 7)
}

// ---------------------------------------------------------------- readout
__global__ void score_kernel(const float* __restrict__ x, const int* __restrict__ tnew,
                             const float* __restrict__ query,
                             const float* __restrict__ W1, const float* __restrict__ b1,
                             const float* __restrict__ W2, const float* __restrict__ b2,
                             float* __restrict__ out) {
    int idx = blockIdx.x;         // b*33+j
    int b = idx / NEG1;
    int k = threadIdx.x;          // 0..63
    __shared__ float v[64];
    int tnode = tnew[idx];
    if (k < 32) v[k] = x[tnode * FEAT + b * DDIM + k];
    else        v[k] = query[b * DDIM + (k - 32)];
    __syncthreads();
    float acc = b1[k];
    #pragma unroll
    for (int l = 0; l < 64; l++) acc = fmaf(v[l], W1[l * 64 + k], acc);
    acc = fmaxf(acc, 0.f);
    float p = acc * W2[k];
    #pragma unroll
    for (int m = 32; m >= 1; m >>= 1) p += __shfl_xor(p, m);
    if (k == 0) out[idx] = p + b2[0];
}

// ---------------------------------------------------------------- launch
extern "C" void kernel_launch(void* const* d_in, const int* in_sizes, int n_in,
                              void* d_out, int out_size, void* d_ws, size_t ws_size,
                              hipStream_t stream) {
    const int* edge_src  = (const int*)d_in[0];
    const int* edge_dst  = (const int*)d_in[1];
    const int* edge_type = (const int*)d_in[2];
    const int* h_index   = (const int*)d_in[3];
    const int* t_index   = (const int*)d_in[4];
    const int* r_index   = (const int*)d_in[5];
    const float* rel_query = (const float*)d_in[7];
    const float* Wrel    = (const float*)d_in[8];
    const float* brel    = (const float*)d_in[9];
    const float* Wlin    = (const float*)d_in[10];
    const float* blin    = (const float*)d_in[11];
    const float* ln_g    = (const float*)d_in[12];
    const float* ln_b    = (const float*)d_in[13];
    const float* W1      = (const float*)d_in[14];
    const float* b1      = (const float*)d_in[15];
    const float* W2      = (const float*)d_in[16];
    const float* b2      = (const float*)d_in[17];

    const int N  = NNODE;
    const int E  = in_sizes[0];
    const int E2 = 2 * E;

    char* p = (char*)d_ws;
    auto carve = [&](size_t bytes) {
        void* r = (void*)p;
        p += (bytes + 255) & ~(size_t)255;
        return r;
    };
    float* x0      = (float*)carve((size_t)N * FEAT * 4);
    float* x1      = (float*)carve((size_t)N * FEAT * 4);
    int*   cnt     = (int*)carve((size_t)N * 4);
    int*   row_ptr = (int*)carve((size_t)(N + 1) * 4);
    int*   cursor  = (int*)carve((size_t)N * 4);
    int*   bsum    = (int*)carve((size_t)128 * 4);
    int*   csr_pack= (int*)carve((size_t)E2 * 4);
    float* dinv    = (float*)carve((size_t)N * 4);
    float* logdeg  = (float*)carve((size_t)N * 4);
    float* scn     = (float*)carve((size_t)N * 4);
    float* meanp   = (float*)carve(16);
    float* rel_all = (float*)carve((size_t)NLAYER * NRELX2 * DDIM * 4);
    unsigned short* bp = (unsigned short*)carve((size_t)NLAYER * BPSZ * 2);
    int*   h0      = (int*)carve(BS * 4);
    int*   r0      = (int*)carve(BS * 4);
    float* query   = (float*)carve(BS * DDIM * 4);
    int*   tnew    = (int*)carve(BS * NEG1 * 4);

    hipMemsetAsync(cnt, 0, (size_t)N * 4, stream);
    hipMemsetAsync(cursor, 0, (size_t)N * 4, stream);

    int eb = (E2 + 255) / 256;
    count_kernel<<<eb, 256, 0, stream>>>(edge_src, edge_dst, cnt, E);
    scanA_kernel<<<SCB, 256, 0, stream>>>(cnt, row_ptr, bsum, N);
    scanB_kernel<<<1, 128, 0, stream>>>(bsum, SCB);
    scanC_kernel<<<SCB, 256, 0, stream>>>(bsum, row_ptr, N);
    fill_kernel<<<eb, 256, 0, stream>>>(edge_src, edge_dst, edge_type, row_ptr,
                                        cursor, csr_pack, E);
    deg_kernel<<<(N + 255) / 256, 256, 0, stream>>>(cnt, dinv, logdeg, N);
    mean_kernel<<<1, 256, 0, stream>>>(logdeg, meanp, N);
    sc_kernel<<<(N + 255) / 256, 256, 0, stream>>>(logdeg, meanp, scn, N);
    prep_kernel<<<1, 256, 0, stream>>>(h_index, t_index, r_index, rel_query,
                                       h0, r0, query, tnew);
    rel_kernel<<<(NLAYER * NRELX2 * DDIM + 255) / 256, 256, 0, stream>>>(
        rel_query, Wrel, brel, rel_all);
    bpack_kernel<<<(NLAYER * BPSZ + 255) / 256, 256, 0, stream>>>(Wlin, bp);
    init_x_kernel<<<(N * FEAT + 255) / 256, 256, 0, stream>>>(x0, h0, query);

    float* xin = x0;
    float* xout = x1;
    for (int i = 0; i < NLAYER; ++i) {
        layer_kernel<<<N / NPB, 256, 0, stream>>>(
            xin, xout, row_ptr, csr_pack,
            rel_all + (size_t)i * NRELX2 * DDIM,
            bp + (size_t)i * BPSZ,
            blin + (size_t)i * DDIM,
            ln_g + (size_t)i * DDIM,
            ln_b + (size_t)i * DDIM,
            dinv, scn, h0, query);
        float* tmp = xin; xin = xout; xout = tmp;
    }

    score_kernel<<<BS * NEG1, 64, 0, stream>>>(xin, tnew, query, W1, b1, W2, b2,
                                               (float*)d_out);
}

// Round 20
// 410.430 us; speedup vs baseline: 1.3387x; 1.3387x over previous
//
#include <hip/hip_runtime.h>
#include <hip/hip_bf16.h>

// Problem constants fixed by setup_inputs()
#define NNODE   20000
#define BS      8
#define NEG1    33
#define DDIM    32
#define NLAYER  6
#define NRELX2  128     // 2*N_REL
#define FEAT    256     // BS*DDIM
#define INW     416     // 13*DDIM
#define NPB     4       // nodes per block -> 32 A-rows, grid 5000
#define BPSZ    (13 * 2 * 2 * 64 * 8)   // per-layer packed-B ushorts (26624)
#define SCB     ((NNODE + 255) / 256)   // scan blocks (79)

typedef __attribute__((ext_vector_type(8))) short s16x8;
typedef __attribute__((ext_vector_type(4))) float f32x4;

__device__ inline unsigned short bf16_rn(float f) {
    unsigned u = __float_as_uint(f);
    u += 0x7FFF + ((u >> 16) & 1);
    return (unsigned short)(u >> 16);
}
__device__ inline float bf16_f(unsigned short h) {
    return __uint_as_float(((unsigned)h) << 16);
}

// ---------------------------------------------------------------- precompute
__global__ void count_kernel(const int* __restrict__ es, const int* __restrict__ ed,
                             int* __restrict__ cnt, int E) {
    int i = blockIdx.x * 256 + threadIdx.x;
    if (i >= 2 * E) return;
    int dst = (i < E) ? ed[i] : es[i - E];
    atomicAdd(&cnt[dst], 1);
}

// hierarchical scan: A) per-block inclusive scan + block sums
__global__ void scanA_kernel(const int* __restrict__ cnt, int* __restrict__ row_ptr,
                             int* __restrict__ bsum, int N) {
    __shared__ int sh[256];
    int i = blockIdx.x * 256 + threadIdx.x;
    int v = (i < N) ? cnt[i] : 0;
    sh[threadIdx.x] = v;
    __syncthreads();
    #pragma unroll
    for (int off = 1; off < 256; off <<= 1) {
        int t = (threadIdx.x >= off) ? sh[threadIdx.x - off] : 0;
        __syncthreads();
        sh[threadIdx.x] += t;
        __syncthreads();
    }
    if (i < N) row_ptr[i + 1] = sh[threadIdx.x];
    if (threadIdx.x == 255) bsum[blockIdx.x] = sh[255];
}

// B) exclusive scan of block sums (one small block)
__global__ void scanB_kernel(int* __restrict__ bsum, int NB) {
    __shared__ int sh[128];
    int t = threadIdx.x;
    int v = (t < NB) ? bsum[t] : 0;
    sh[t] = v;
    __syncthreads();
    #pragma unroll
    for (int off = 1; off < 128; off <<= 1) {
        int x = (t >= off) ? sh[t - off] : 0;
        __syncthreads();
        sh[t] += x;
        __syncthreads();
    }
    if (t < NB) bsum[t] = sh[t] - v;   // exclusive
}

// C) add block offsets
__global__ void scanC_kernel(const int* __restrict__ bsum, int* __restrict__ row_ptr, int N) {
    int i = blockIdx.x * 256 + threadIdx.x;
    if (i == 0) row_ptr[0] = 0;
    if (i < N) row_ptr[i + 1] += bsum[blockIdx.x];
}

// csr_pack = (src << 16) | etype   (src < 20000 < 65536, etype < 128)
__global__ void fill_kernel(const int* __restrict__ es, const int* __restrict__ ed,
                            const int* __restrict__ et, const int* __restrict__ row_ptr,
                            int* __restrict__ cursor, int* __restrict__ csr_pack, int E) {
    int i = blockIdx.x * 256 + threadIdx.x;
    if (i >= 2 * E) return;
    int src, dst, ty;
    if (i < E) { src = es[i]; dst = ed[i]; ty = et[i]; }
    else       { src = ed[i - E]; dst = es[i - E]; ty = et[i - E] + 64; }
    int pos = row_ptr[dst] + atomicAdd(&cursor[dst], 1);
    csr_pack[pos] = (src << 16) | ty;
}

__global__ void deg_kernel(const int* __restrict__ cnt, float* __restrict__ dinv,
                           float* __restrict__ logdeg, int N) {
    int n = blockIdx.x * 256 + threadIdx.x;
    if (n >= N) return;
    float deg = (float)cnt[n] + 1.0f;
    dinv[n] = 1.0f / deg;
    logdeg[n] = logf(deg);
}

__global__ void mean_kernel(const float* __restrict__ logdeg, float* __restrict__ meanout, int N) {
    __shared__ float sh[256];
    float s = 0.f;
    for (int i = threadIdx.x; i < N; i += 256) s += logdeg[i];
    sh[threadIdx.x] = s;
    __syncthreads();
    for (int off = 128; off > 0; off >>= 1) {
        if (threadIdx.x < off) sh[threadIdx.x] += sh[threadIdx.x + off];
        __syncthreads();
    }
    if (threadIdx.x == 0) meanout[0] = sh[0] / (float)N;
}

__global__ void sc_kernel(const float* __restrict__ logdeg, const float* __restrict__ meanp,
                          float* __restrict__ sc, int N) {
    int n = blockIdx.x * 256 + threadIdx.x;
    if (n >= N) return;
    sc[n] = logdeg[n] / meanp[0];
}

__global__ void prep_kernel(const int* __restrict__ h_index, const int* __restrict__ t_index,
                            const int* __restrict__ r_index, const float* __restrict__ rel_query,
                            int* __restrict__ h0, int* __restrict__ r0,
                            float* __restrict__ query, int* __restrict__ tnew) {
    __shared__ int s_isneg[BS];
    __shared__ int s_r0[BS];
    int t = threadIdx.x;
    if (t < BS) {
        int b = t;
        int hv = h_index[b * NEG1];
        int all = 1;
        for (int j = 1; j < NEG1; j++) all &= (h_index[b * NEG1 + j] == hv);
        s_isneg[b] = all;
        int h0v = all ? hv : t_index[b * NEG1];
        int r0v = all ? r_index[b * NEG1] : r_index[b * NEG1] + 64;
        s_r0[b] = r0v;
        h0[b] = h0v;
        r0[b] = r0v;
    }
    __syncthreads();
    {
        int b = t >> 5, dd = t & 31;
        query[t] = rel_query[s_r0[b] * DDIM + dd];
    }
    for (int idx = t; idx < BS * NEG1; idx += 256) {
        int b = idx / NEG1;
        tnew[idx] = s_isneg[b] ? t_index[idx] : h_index[idx];
    }
}

__global__ void rel_kernel(const float* __restrict__ rel_query, const float* __restrict__ Wrel,
                           const float* __restrict__ brel, float* __restrict__ rel_all) {
    int idx = blockIdx.x * 256 + threadIdx.x;
    if (idx >= NLAYER * NRELX2 * DDIM) return;
    int i  = idx >> 12;          // / 4096
    int q  = (idx >> 5) & 127;
    int dd = idx & 31;
    float acc = brel[i * DDIM + dd];
    #pragma unroll
    for (int k = 0; k < DDIM; k++)
        acc = fmaf(rel_query[q * DDIM + k], Wrel[i * DDIM * DDIM + k * DDIM + dd], acc);
    rel_all[idx] = acc;
}

// Packed split-bf16 B fragments for mfma_f32_16x16x32_bf16.
// Flat layout: ((((layer*13 + j)*2 + half)*2 + term)*64 + lane)*8 + e
__global__ void bpack_kernel(const float* __restrict__ Wlin, unsigned short* __restrict__ bp) {
    int idx = blockIdx.x * 256 + threadIdx.x;
    if (idx >= NLAYER * BPSZ) return;
    int e    = idx & 7;
    int lane = (idx >> 3) & 63;
    int term = (idx >> 9) & 1;
    int half = (idx >> 10) & 1;
    int jl   = idx >> 11;
    int j    = jl % 13;
    int layer = jl / 13;
    int col = half * 16 + (lane & 15);
    int kk  = (lane >> 4) * 8 + e;
    int row;
    if (j == 0) row = kk;
    else { int s = (j - 1) & 3, scl = (j - 1) >> 2; row = 32 + (kk * 4 + s) * 3 + scl; }
    float wv = Wlin[(layer * INW + row) * DDIM + col];
    unsigned short hi = bf16_rn(wv);
    bp[idx] = (term == 0) ? hi : bf16_rn(wv - bf16_f(hi));
}

__global__ void init_x_kernel(float* __restrict__ x, const int* __restrict__ h0,
                              const float* __restrict__ query) {
    int i = blockIdx.x * 256 + threadIdx.x;
    if (i >= NNODE * FEAT) return;
    int n = i >> 8;
    int t = i & 255;
    int b = t >> 5;
    x[i] = (h0[b] == n) ? query[t] : 0.f;
}

// ---------------------------------------------------------------- main layer
// Phases: [stats x4 nodes (rel read from L1-resident global)] [A(split bf16)
// ->LDS] [MFMA GEMM] [C overlaid into A region] [LN/residual].
// LDS = 21.5 KB only -> ~7 blocks/CU for latency hiding.

#define STATS_COMP(U, NODE) {                                                 \
    int n_ = (NODE);                                                          \
    float bv_ = (h0b == n_) ? q : 0.f;                                        \
    float sum_ = bv_, ssq_ = bv_ * bv_, vmx_ = bv_, vmn_ = bv_;               \
    int e0_ = row_ptr[n_], e1_ = row_ptr[n_ + 1];                             \
    xm##U = x_in[n_ * FEAT + t];                                              \
    int e_ = e0_;                                                             \
    for (; e_ + 3 < e1_; e_ += 4) {                                           \
        int pa_ = csr_pack[e_];                                               \
        int pb_ = csr_pack[e_ + 1];                                           \
        int pc_ = csr_pack[e_ + 2];                                           \
        int pd_ = csr_pack[e_ + 3];                                           \
        float xa_ = x_in[(pa_ >> 16) * FEAT + t];                             \
        float xb_ = x_in[(pb_ >> 16) * FEAT + t];                             \
        float xc_ = x_in[(pc_ >> 16) * FEAT + t];                             \
        float xd_ = x_in[(pd_ >> 16) * FEAT + t];                             \
        float ra_ = rel_i[((pa_ & 0xFFFF) << 5) + dd];                        \
        float rb_ = rel_i[((pb_ & 0xFFFF) << 5) + dd];                        \
        float rc_ = rel_i[((pc_ & 0xFFFF) << 5) + dd];                        \
        float rd_ = rel_i[((pd_ & 0xFFFF) << 5) + dd];                        \
        float ma_ = xa_ * ra_, mb_ = xb_ * rb_;                               \
        float mc_ = xc_ * rc_, md_ = xd_ * rd_;                               \
        sum_ += ((ma_ + mb_) + (mc_ + md_));                                  \
        ssq_ = fmaf(ma_, ma_, ssq_); ssq_ = fmaf(mb_, mb_, ssq_);             \
        ssq_ = fmaf(mc_, mc_, ssq_); ssq_ = fmaf(md_, md_, ssq_);             \
        vmx_ = fmaxf(vmx_, fmaxf(fmaxf(ma_, mb_), fmaxf(mc_, md_)));         \
        vmn_ = fminf(vmn_, fminf(fminf(ma_, mb_), fminf(mc_, md_)));         \
    }                                                                         \
    for (; e_ < e1_; ++e_) {                                                  \
        int p_  = csr_pack[e_];                                               \
        float m_ = x_in[(p_ >> 16) * FEAT + t]                                \
                   * rel_i[((p_ & 0xFFFF) << 5) + dd];                        \
        sum_ += m_; ssq_ = fmaf(m_, m_, ssq_);                                \
        vmx_ = fmaxf(vmx_, m_); vmn_ = fminf(vmn_, m_);                       \
    }                                                                         \
    float dv_ = dinv[n_];                                                     \
    mean##U = sum_ * dv_;                                                     \
    float sq_ = ssq_ * dv_;                                                   \
    mx##U = vmx_; mn##U = vmn_;                                               \
    sd##U = sqrtf(fmaxf(sq_ - mean##U * mean##U, 1e-6f));                     \
    float sv_ = sc[n_];                                                       \
    sv##U = sv_; s2##U = 1.0f / fmaxf(sv_, 0.01f);                            \
}

#define SDECL(U) float xm##U, mean##U, mx##U, mn##U, sd##U, sv##U, s2##U;

#define AW1(ROW, C, V) {                                                      \
    unsigned short h_ = bf16_rn(V);                                           \
    s_A[0][ROW][(C) * 32 + dd] = h_;                                          \
    s_A[1][ROW][(C) * 32 + dd] = bf16_rn((V) - bf16_f(h_));                   \
}

#define AWRITE(U, NL) {                                                       \
    int row_ = (NL) * 8 + b;                                                  \
    AW1(row_, 0, xm##U)                                                       \
    AW1(row_, 1, mean##U)                                                     \
    AW1(row_, 2, mx##U)                                                       \
    AW1(row_, 3, mn##U)                                                       \
    AW1(row_, 4, sd##U)                                                       \
}

#define LNF(U, NL) {                                                          \
    int row_ = (NL) * 8 + b;                                                  \
    float v_ = s_C[row_ * 33 + dd]                                            \
             + sv##U * s_C[1056 + row_ * 33 + dd]                             \
             + s2##U * s_C[2112 + row_ * 33 + dd] + bl;                       \
    float s1_ = v_;                                                           \
    s1_ += __shfl_xor(s1_, 16, 32); s1_ += __shfl_xor(s1_, 8, 32);            \
    s1_ += __shfl_xor(s1_, 4, 32);  s1_ += __shfl_xor(s1_, 2, 32);            \
    s1_ += __shfl_xor(s1_, 1, 32);                                            \
    float lm_ = s1_ * (1.0f / 32.0f);                                         \
    float dl_ = v_ - lm_;                                                     \
    float p2_ = dl_ * dl_;                                                    \
    p2_ += __shfl_xor(p2_, 16, 32); p2_ += __shfl_xor(p2_, 8, 32);            \
    p2_ += __shfl_xor(p2_, 4, 32);  p2_ += __shfl_xor(p2_, 2, 32);            \
    p2_ += __shfl_xor(p2_, 1, 32);                                            \
    float var_ = p2_ * (1.0f / 32.0f);                                        \
    float y_ = dl_ / sqrtf(var_ + 1e-5f) * gdd + bdd;                         \
    y_ = fmaxf(y_, 0.0f);                                                     \
    x_out[(nbase + (NL)) * FEAT + t] = y_ + xm##U;                            \
}

__global__ __launch_bounds__(256, 6) void layer_kernel(
    const float* __restrict__ x_in, float* __restrict__ x_out,
    const int* __restrict__ row_ptr, const int* __restrict__ csr_pack,
    const float* __restrict__ rel_i,           // [128][32], L1-resident
    const unsigned short* __restrict__ bp_i,   // packed split-bf16 B frags
    const float* __restrict__ blin_i, const float* __restrict__ g_i,
    const float* __restrict__ b_i,
    const float* __restrict__ dinv, const float* __restrict__ sc,
    const int* __restrict__ h0, const float* __restrict__ query) {
    int t  = threadIdx.x;
    int b  = t >> 5, dd = t & 31;
    int l  = t & 63;
    int w  = t >> 6;
    // 21 KB: split-bf16 A; C planes (12.7 KB) overlay it after MFMA reads.
    __shared__ __align__(16) unsigned short s_A[2][32][168];
    float* s_C = (float*)&s_A[0][0][0];

    float q   = query[t];
    int   h0b = h0[b];
    float gdd = g_i[dd], bdd = b_i[dd], bl = blin_i[dd];

    int nbase = blockIdx.x * NPB;
    SDECL(0) SDECL(1) SDECL(2) SDECL(3)
    STATS_COMP(0, nbase + 0)
    STATS_COMP(1, nbase + 1)
    STATS_COMP(2, nbase + 2)
    STATS_COMP(3, nbase + 3)

    // phase 2: A rows (split bf16) into LDS
    AWRITE(0, 0) AWRITE(1, 1) AWRITE(2, 2) AWRITE(3, 3)
    __syncthreads();

    // phase 3: MFMA GEMM. wave w: tile = w>>1, half = w&1.
    {
        int tile = w >> 1, half = w & 1;
        int arow = tile * 16 + (l & 15);
        int koff = (l >> 4) * 8;
        f32x4 acc0 = {0.f, 0.f, 0.f, 0.f};
        f32x4 acc1 = {0.f, 0.f, 0.f, 0.f};
        f32x4 acc2 = {0.f, 0.f, 0.f, 0.f};
        #pragma unroll
        for (int j = 0; j < 13; ++j) {
            int ac = (j == 0) ? 0 : 1 + ((j - 1) & 3);
            s16x8 ah = *(const s16x8*)&s_A[0][arow][ac * 32 + koff];
            s16x8 al = *(const s16x8*)&s_A[1][arow][ac * 32 + koff];
            const unsigned short* pb = bp_i + (((j * 2 + half) * 2 + 0) * 64 + l) * 8;
            s16x8 bh = *(const s16x8*)pb;
            s16x8 bl2 = *(const s16x8*)(pb + 512);   // term=1 stride 64*8
            if (j <= 4) {
                acc0 = __builtin_amdgcn_mfma_f32_16x16x32_bf16(ah, bh,  acc0, 0, 0, 0);
                acc0 = __builtin_amdgcn_mfma_f32_16x16x32_bf16(ah, bl2, acc0, 0, 0, 0);
                acc0 = __builtin_amdgcn_mfma_f32_16x16x32_bf16(al, bh,  acc0, 0, 0, 0);
            } else if (j <= 8) {
                acc1 = __builtin_amdgcn_mfma_f32_16x16x32_bf16(ah, bh,  acc1, 0, 0, 0);
                acc1 = __builtin_amdgcn_mfma_f32_16x16x32_bf16(ah, bl2, acc1, 0, 0, 0);
                acc1 = __builtin_amdgcn_mfma_f32_16x16x32_bf16(al, bh,  acc1, 0, 0, 0);
            } else {
                acc2 = __builtin_amdgcn_mfma_f32_16x16x32_bf16(ah, bh,  acc2, 0, 0, 0);
                acc2 = __builtin_amdgcn_mfma_f32_16x16x32_bf16(ah, bl2, acc2, 0, 0, 0);
                acc2 = __builtin_amdgcn_mfma_f32_16x16x32_bf16(al, bh,  acc2, 0, 0, 0);
            }
        }
        __syncthreads();   // all waves done reading A -> safe to overlay C
        // C/D layout (verified): col = lane&15, row = (lane>>4)*4 + reg
        int crow = tile * 16 + ((l >> 4) << 2);
        int ccol = half * 16 + (l & 15);
        #pragma unroll
        for (int r = 0; r < 4; ++r) {
            s_C[(crow + r) * 33 + ccol]        = acc0[r];
            s_C[1056 + (crow + r) * 33 + ccol] = acc1[r];
            s_C[2112 + (crow + r) * 33 + ccol] = acc2[r];
        }
    }
    __syncthreads();

    // phase 4: combine + LayerNorm + ReLU + residual
    LNF(0, 0) LNF(1, 1) LNF(2, 2) LNF(3, 3)
}

// ---------------------------------------------------------------- readout
__global__ void score_kernel(const float* __restrict__ x, const int* __restrict__ tnew,
                             const float* __restrict__ query,
                             const float* __restrict__ W1, const float* __restrict__ b1,
                             const float* __restrict__ W2, const float* __restrict__ b2,
                             float* __restrict__ out) {
    int idx = blockIdx.x;         // b*33+j
    int b = idx / NEG1;
    int k = threadIdx.x;          // 0..63
    __shared__ float v[64];
    int tnode = tnew[idx];
    if (k < 32) v[k] = x[tnode * FEAT + b * DDIM + k];
    else        v[k] = query[b * DDIM + (k - 32)];
    __syncthreads();
    float acc = b1[k];
    #pragma unroll
    for (int l = 0; l < 64; l++) acc = fmaf(v[l], W1[l * 64 + k], acc);
    acc = fmaxf(acc, 0.f);
    float p = acc * W2[k];
    #pragma unroll
    for (int m = 32; m >= 1; m >>= 1) p += __shfl_xor(p, m);
    if (k == 0) out[idx] = p + b2[0];
}

// ---------------------------------------------------------------- launch
extern "C" void kernel_launch(void* const* d_in, const int* in_sizes, int n_in,
                              void* d_out, int out_size, void* d_ws, size_t ws_size,
                              hipStream_t stream) {
    const int* edge_src  = (const int*)d_in[0];
    const int* edge_dst  = (const int*)d_in[1];
    const int* edge_type = (const int*)d_in[2];
    const int* h_index   = (const int*)d_in[3];
    const int* t_index   = (const int*)d_in[4];
    const int* r_index   = (const int*)d_in[5];
    const float* rel_query = (const float*)d_in[7];
    const float* Wrel    = (const float*)d_in[8];
    const float* brel    = (const float*)d_in[9];
    const float* Wlin    = (const float*)d_in[10];
    const float* blin    = (const float*)d_in[11];
    const float* ln_g    = (const float*)d_in[12];
    const float* ln_b    = (const float*)d_in[13];
    const float* W1      = (const float*)d_in[14];
    const float* b1      = (const float*)d_in[15];
    const float* W2      = (const float*)d_in[16];
    const float* b2      = (const float*)d_in[17];

    const int N  = NNODE;
    const int E  = in_sizes[0];
    const int E2 = 2 * E;

    char* p = (char*)d_ws;
    auto carve = [&](size_t bytes) {
        void* r = (void*)p;
        p += (bytes + 255) & ~(size_t)255;
        return r;
    };
    float* x0      = (float*)carve((size_t)N * FEAT * 4);
    float* x1      = (float*)carve((size_t)N * FEAT * 4);
    int*   cnt     = (int*)carve((size_t)N * 4);
    int*   row_ptr = (int*)carve((size_t)(N + 1) * 4);
    int*   cursor  = (int*)carve((size_t)N * 4);
    int*   bsum    = (int*)carve((size_t)128 * 4);
    int*   csr_pack= (int*)carve((size_t)E2 * 4);
    float* dinv    = (float*)carve((size_t)N * 4);
    float* logdeg  = (float*)carve((size_t)N * 4);
    float* scn     = (float*)carve((size_t)N * 4);
    float* meanp   = (float*)carve(16);
    float* rel_all = (float*)carve((size_t)NLAYER * NRELX2 * DDIM * 4);
    unsigned short* bp = (unsigned short*)carve((size_t)NLAYER * BPSZ * 2);
    int*   h0      = (int*)carve(BS * 4);
    int*   r0      = (int*)carve(BS * 4);
    float* query   = (float*)carve(BS * DDIM * 4);
    int*   tnew    = (int*)carve(BS * NEG1 * 4);

    hipMemsetAsync(cnt, 0, (size_t)N * 4, stream);
    hipMemsetAsync(cursor, 0, (size_t)N * 4, stream);

    int eb = (E2 + 255) / 256;
    count_kernel<<<eb, 256, 0, stream>>>(edge_src, edge_dst, cnt, E);
    scanA_kernel<<<SCB, 256, 0, stream>>>(cnt, row_ptr, bsum, N);
    scanB_kernel<<<1, 128, 0, stream>>>(bsum, SCB);
    scanC_kernel<<<SCB, 256, 0, stream>>>(bsum, row_ptr, N);
    fill_kernel<<<eb, 256, 0, stream>>>(edge_src, edge_dst, edge_type, row_ptr,
                                        cursor, csr_pack, E);
    deg_kernel<<<(N + 255) / 256, 256, 0, stream>>>(cnt, dinv, logdeg, N);
    mean_kernel<<<1, 256, 0, stream>>>(logdeg, meanp, N);
    sc_kernel<<<(N + 255) / 256, 256, 0, stream>>>(logdeg, meanp, scn, N);
    prep_kernel<<<1, 256, 0, stream>>>(h_index, t_index, r_index, rel_query,
                                       h0, r0, query, tnew);
    rel_kernel<<<(NLAYER * NRELX2 * DDIM + 255) / 256, 256, 0, stream>>>(
        rel_query, Wrel, brel, rel_all);
    bpack_kernel<<<(NLAYER * BPSZ + 255) / 256, 256, 0, stream>>>(Wlin, bp);
    init_x_kernel<<<(N * FEAT + 255) / 256, 256, 0, stream>>>(x0, h0, query);

    float* xin = x0;
    float* xout = x1;
    for (int i = 0; i < NLAYER; ++i) {
        layer_kernel<<<N / NPB, 256, 0, stream>>>(
            xin, xout, row_ptr, csr_pack,
            rel_all + (size_t)i * NRELX2 * DDIM,
            bp + (size_t)i * BPSZ,
            blin + (size_t)i * DDIM,
            ln_g + (size_t)i * DDIM,
            ln_b + (size_t)i * DDIM,
            dinv, scn, h0, query);
        float* tmp = xin; xin = xout; xout = tmp;
    }

    score_kernel<<<BS * NEG1, 64, 0, stream>>>(xin, tnew, query, W1, b1, W2, b2,
                                               (float*)d_out);
}